// Round 2
// baseline (206.972 us; speedup 1.0000x reference)
//
#include <hip/hip_runtime.h>

typedef __attribute__((ext_vector_type(8))) short          bf16x8;
typedef __attribute__((ext_vector_type(8))) unsigned short u16x8;
typedef __attribute__((ext_vector_type(4))) float          f32x4;

union U8 { u16x8 u; bf16x8 b; };

__device__ __forceinline__ unsigned short f2bf(float f){
  unsigned u = __float_as_uint(f);
  return (unsigned short)((u + 0x7fffu + ((u >> 16) & 1u)) >> 16);
}

#define NB  8
#define NN  1024
#define FIN 256
#define NH  8
#define FO  64

// ---------------------------------------------------------------------------
// Stage A: h[b,h,n,o] = sum_f (x*Npost*e_atten)[b,n,f] * w[h,f,o]   (MFMA)
//          writes hT[b,h,o,n] (bf16 workspace), s[b,h,n], d[b,h,n] (fp32)
// grid (4 head-pairs, 16 node-tiles(64), 8 b), block 256 (4 waves)
// ---------------------------------------------------------------------------
__global__ __launch_bounds__(256, 2) void stageA(
    const float* __restrict__ x,
    const float* __restrict__ e_at,
    const float* __restrict__ Np,
    const float* __restrict__ w,
    const float* __restrict__ a_src,
    const float* __restrict__ a_dst,
    unsigned short* __restrict__ hT,
    float* __restrict__ sbuf,
    float* __restrict__ dbuf)
{
  __shared__ unsigned short wT[64 * 264];   // w[h] transposed [o][f] bf16, pad 264
  __shared__ unsigned short tbuf[64 * 72];  // h-tile transpose buffer [o][n], pad 72
  const int t = threadIdx.x;
  const int b = blockIdx.z, n0 = blockIdx.y * 64, h0 = blockIdx.x * 2;
  const int wave = t >> 6, lane = t & 63, quad = lane >> 4, l15 = lane & 15;
  const int nrow = n0 + 16 * wave + l15;    // A-frag row for this lane

  // Build recx A-fragments in registers once (shared by both heads).
  // A-operand layout (16x16x32): A[m=lane&15][k=quad*8+j]
  U8 afr[8];
  {
    const float* ep = e_at + (b * NN + nrow) * FIN;
    const float* np = Np + nrow * FIN;
    const float* xp = x + b * FIN;
    #pragma unroll
    for (int kc = 0; kc < 8; kc++){
      const int k0 = kc * 32 + quad * 8;
      f32x4 e0 = *(const f32x4*)(ep + k0), e1 = *(const f32x4*)(ep + k0 + 4);
      f32x4 q0 = *(const f32x4*)(np + k0), q1 = *(const f32x4*)(np + k0 + 4);
      f32x4 x0 = *(const f32x4*)(xp + k0), x1 = *(const f32x4*)(xp + k0 + 4);
      U8 r;
      #pragma unroll
      for (int j = 0; j < 4; j++){
        r.u[j]     = f2bf(e0[j] * q0[j] * x0[j]);
        r.u[j + 4] = f2bf(e1[j] * q1[j] * x1[j]);
      }
      afr[kc] = r;
    }
  }

  for (int hh = 0; hh < 2; hh++){
    const int h = h0 + hh;
    __syncthreads();                         // prior head done with wT/tbuf
    for (int i = t; i < FIN * FO; i += 256){ // load w[h] transposed into LDS (bf16)
      int o = i & 63, f = i >> 6;
      wT[o * 264 + f] = f2bf(w[(h * FIN + f) * FO + o]);
    }
    __syncthreads();

    f32x4 acc[4] = {};                       // 4 o-subtiles, rows 16*wave..+16
    #pragma unroll
    for (int kc = 0; kc < 8; kc++){
      const int k0 = kc * 32 + quad * 8;
      #pragma unroll
      for (int ss = 0; ss < 4; ss++){
        U8 bf; bf.u = *(const u16x8*)(wT + (16 * ss + l15) * 264 + k0);
        acc[ss] = __builtin_amdgcn_mfma_f32_16x16x32_bf16(afr[kc].b, bf.b, acc[ss], 0, 0, 0);
      }
    }

    // C/D: col(o)=lane&15, row(n)=quad*4+reg.  Transpose to hT via LDS.
    #pragma unroll
    for (int ss = 0; ss < 4; ss++)
      #pragma unroll
      for (int i = 0; i < 4; i++)
        tbuf[(16 * ss + l15) * 72 + 16 * wave + quad * 4 + i] = f2bf(acc[ss][i]);
    __syncthreads();
    {
      const int o = t >> 2, c0 = (t & 3) * 16;
      unsigned short* dst = hT + ((b * NH + h) * FO + o) * NN + n0 + c0;
      *(u16x8*)(dst)     = *(const u16x8*)(tbuf + o * 72 + c0);
      *(u16x8*)(dst + 8) = *(const u16x8*)(tbuf + o * 72 + c0 + 8);
    }
    // s = h . a_src, d = h . a_dst  (reduce over o via shuffles)
    {
      float as4[4], ad4[4];
      #pragma unroll
      for (int ss = 0; ss < 4; ss++){
        as4[ss] = a_src[h * FO + 16 * ss + l15];
        ad4[ss] = a_dst[h * FO + 16 * ss + l15];
      }
      #pragma unroll
      for (int i = 0; i < 4; i++){
        float ps = 0.f, pd = 0.f;
        #pragma unroll
        for (int ss = 0; ss < 4; ss++){ ps += acc[ss][i] * as4[ss]; pd += acc[ss][i] * ad4[ss]; }
        #pragma unroll
        for (int off = 1; off < 16; off <<= 1){
          ps += __shfl_xor(ps, off);
          pd += __shfl_xor(pd, off);
        }
        if (l15 == 0){
          const int row = n0 + 16 * wave + quad * 4 + i;
          sbuf[(b * NH + h) * NN + row] = ps;
          dbuf[(b * NH + h) * NN + row] = pd;
        }
      }
    }
  }
}

// ---------------------------------------------------------------------------
// Stage B: out[b,n,o] = mask * ( bias + (1/8) sum_h  (P_h @ h_h)[n,o] / l_h[n] )
//   P = adj ? exp(leaky(s_n + d_m)) : 0   (no max-subtract: logits are O(0.3))
// grid (32 node-tiles(32), 8 b), block 512 (8 waves = 8 heads)
// ---------------------------------------------------------------------------
__global__ __launch_bounds__(512, 2) void stageB(
    const int* __restrict__ A,
    const unsigned short* __restrict__ hT,
    const float* __restrict__ sbuf,
    const float* __restrict__ dbuf,
    const float* __restrict__ bias,
    const float* __restrict__ mz,
    float* __restrict__ out)
{
  __shared__ float s_l[NH * 32];
  __shared__ float d_l[NH * 32];
  __shared__ int   a_l[32 * 33];               // stride 33: conflict-free rows
  __shared__ unsigned short p_l[NH * 32 * 40]; // stride 40: 2-way (free) on frag reads
  __shared__ float l_l[NH * 32];
  __shared__ float oacc[32 * 64];
  const int t = threadIdx.x;
  const int b = blockIdx.y, n0 = blockIdx.x * 32;
  const int lane = t & 63, quad = lane >> 4, l15 = lane & 15;
  const int h = t >> 6;                        // wave = head
  const int pr = lane & 31, pmh = lane >> 5;

  for (int i = t; i < NH * 32; i += 512)
    s_l[i] = sbuf[(b * NH + (i >> 5)) * NN + n0 + (i & 31)];
  for (int i = t; i < 2048; i += 512) oacc[i] = 0.f;
  __syncthreads();

  const float sv = s_l[h * 32 + pr];
  const unsigned short* hTb = hT + (b * NH + h) * FO * NN;
  const int lr = t >> 4, lm = (t * 2) & 31;
  const int* Abase = A + (b * NN + n0 + lr) * NN + lm;
  const float* dsrc = dbuf + (b * NH + ((t >> 5) & 7)) * NN + (t & 31);

  // software-pipelined prefetch regs (adjacency chunk, d chunk, h B-frags)
  int ar0 = Abase[0], ar1 = Abase[1];
  float dr = (t < 256) ? dsrc[0] : 0.f;
  U8 bfr[4], bnx[4];
  #pragma unroll
  for (int ss = 0; ss < 4; ss++)
    bfr[ss].u = *(const u16x8*)(hTb + (16 * ss + l15) * NN + quad * 8);

  float lpart = 0.f;
  f32x4 acc[2][4] = {};

  for (int mc = 0; mc < NN; mc += 32){
    __syncthreads();                        // prev P consumed, a_l/d_l free
    a_l[lr * 33 + lm]     = ar0;
    a_l[lr * 33 + lm + 1] = ar1;
    if (t < 256) d_l[t] = dr;
    __syncthreads();
    if (mc + 32 < NN){                      // prefetch next chunk (hidden by P+MFMA)
      ar0 = Abase[mc + 32];
      ar1 = Abase[mc + 33];
      if (t < 256) dr = dsrc[mc + 32];
      #pragma unroll
      for (int ss = 0; ss < 4; ss++)
        bnx[ss].u = *(const u16x8*)(hTb + (16 * ss + l15) * NN + mc + 32 + quad * 8);
    }
    // P compute: lane handles row pr, m = pmh*16 + u
    {
      unsigned short pv[16];
      const float* dch = d_l + h * 32;
      const int*  ach = a_l + pr * 33 + pmh * 16;
      #pragma unroll
      for (int u = 0; u < 16; u++){
        const int m = pmh * 16 + u;
        float z = sv + dch[m];
        z = z > 0.f ? z : 0.2f * z;
        float p = (ach[u] > 0) ? __expf(z) : 0.f;
        lpart += p;
        pv[u] = f2bf(p);
      }
      unsigned short* pp = p_l + (h * 32 + pr) * 40 + pmh * 16;
      *(u16x8*)(pp)     = *(const u16x8*)(pv);
      *(u16x8*)(pp + 8) = *(const u16x8*)(pv + 8);
    }
    __syncthreads();
    #pragma unroll
    for (int rh = 0; rh < 2; rh++){
      U8 af; af.u = *(const u16x8*)(p_l + (h * 32 + rh * 16 + l15) * 40 + quad * 8);
      #pragma unroll
      for (int ss = 0; ss < 4; ss++)
        acc[rh][ss] = __builtin_amdgcn_mfma_f32_16x16x32_bf16(af.b, bfr[ss].b, acc[rh][ss], 0, 0, 0);
    }
    #pragma unroll
    for (int ss = 0; ss < 4; ss++) bfr[ss] = bnx[ss];
  }

  // row softmax denominators: combine the two m-halves
  lpart += __shfl_xor(lpart, 32);
  if (lane < 32) l_l[h * 32 + lane] = lpart;
  __syncthreads();

  // normalize per head, average heads into oacc
  #pragma unroll
  for (int rh = 0; rh < 2; rh++)
    #pragma unroll
    for (int ss = 0; ss < 4; ss++)
      #pragma unroll
      for (int i = 0; i < 4; i++){
        const int row = rh * 16 + quad * 4 + i;
        const float v = acc[rh][ss][i] / (8.f * l_l[h * 32 + row]);
        atomicAdd(&oacc[row * 64 + ss * 16 + l15], v);
      }
  __syncthreads();

  for (int i = t; i < 2048; i += 512){
    const int row = i >> 6, o = i & 63;
    out[(b * NN + n0 + row) * FO + o] = (oacc[i] + bias[o]) * mz[b * NN + n0 + row];
  }
}

extern "C" void kernel_launch(void* const* d_in, const int* in_sizes, int n_in,
                              void* d_out, int out_size, void* d_ws, size_t ws_size,
                              hipStream_t stream)
{
  (void)in_sizes; (void)n_in; (void)out_size; (void)ws_size;
  const float* x    = (const float*)d_in[0];
  const int*   A    = (const int*)d_in[1];
  const float* mz   = (const float*)d_in[2];
  // d_in[3] = p_atten, unused by the reference forward body
  const float* e_at = (const float*)d_in[4];
  const float* Np   = (const float*)d_in[5];
  const float* w    = (const float*)d_in[6];
  const float* asrc = (const float*)d_in[7];
  const float* adst = (const float*)d_in[8];
  const float* bias = (const float*)d_in[9];
  float* out = (float*)d_out;

  char* ws = (char*)d_ws;
  unsigned short* hT = (unsigned short*)ws;                  // 8*8*64*1024 bf16 = 8 MB
  float* sbuf = (float*)(ws + 8388608);                      // 256 KB
  float* dbuf = (float*)(ws + 8388608 + 262144);             // 256 KB

  stageA<<<dim3(4, 16, 8), dim3(256), 0, stream>>>(x, e_at, Np, w, asrc, adst, hT, sbuf, dbuf);
  stageB<<<dim3(32, 8), dim3(512), 0, stream>>>(A, hT, sbuf, dbuf, bias, mz, out);
}

// Round 3
// 195.751 us; speedup vs baseline: 1.0573x; 1.0573x over previous
//
#include <hip/hip_runtime.h>

typedef __attribute__((ext_vector_type(8))) short          bf16x8;
typedef __attribute__((ext_vector_type(8))) unsigned short u16x8;
typedef __attribute__((ext_vector_type(4))) unsigned short u16x4;
typedef __attribute__((ext_vector_type(4))) float          f32x4;
typedef __attribute__((ext_vector_type(4))) int            i32x4;
typedef __attribute__((ext_vector_type(4))) unsigned int   u32x4;

union U8 { u16x8 u; bf16x8 b; u32x4 w; };

__device__ __forceinline__ unsigned short f2bf(float f){
  unsigned u = __float_as_uint(f);
  return (unsigned short)((u + 0x7fffu + ((u >> 16) & 1u)) >> 16);
}
// pack two floats to bf16x2 (round-half-up): lo -> low16, hi -> high16.
// exact 0.0 stays exact 0 (mask correctness).
__device__ __forceinline__ unsigned pack_bf16(float lo, float hi){
  unsigned a = __float_as_uint(hi) + 0x8000u;
  unsigned b = __float_as_uint(lo) + 0x8000u;
  return __builtin_amdgcn_perm(a, b, 0x07060302u);
}

#define NN  1024
#define FIN 256
#define NH  8
#define FO  64

// ---------------------------------------------------------------------------
// Stage 0: recx[b,n,f] = x[b,f]*Np[n,f]*e_at[b,n,f]  (bf16)
//          wB[h,o,f]   = w[h,f,o]                    (bf16 transposed)
// ---------------------------------------------------------------------------
__global__ __launch_bounds__(256) void stage0(
    const float* __restrict__ x, const float* __restrict__ e_at,
    const float* __restrict__ Np, const float* __restrict__ w,
    unsigned short* __restrict__ recx, unsigned short* __restrict__ wB)
{
  const int tid = blockIdx.x * 256 + threadIdx.x;
  for (int g = tid; g < 262144; g += 65536){      // 2M elems / 8
    const int f8 = (g & 31) * 8;
    const int n  = (g >> 5) & 1023;
    const int b  = g >> 15;
    const float* ep = e_at + (b * NN + n) * FIN + f8;
    const float* qp = Np + n * FIN + f8;
    const float* xp = x + b * FIN + f8;
    f32x4 e0 = *(const f32x4*)ep, e1 = *(const f32x4*)(ep + 4);
    f32x4 q0 = *(const f32x4*)qp, q1 = *(const f32x4*)(qp + 4);
    f32x4 x0 = *(const f32x4*)xp, x1 = *(const f32x4*)(xp + 4);
    u16x8 r;
    #pragma unroll
    for (int j = 0; j < 4; j++){
      r[j]     = f2bf(e0[j] * q0[j] * x0[j]);
      r[j + 4] = f2bf(e1[j] * q1[j] * x1[j]);
    }
    *(u16x8*)(recx + g * 8) = r;
  }
  for (int i = tid; i < 131072; i += 65536){      // w transpose
    const int o = i & 63, f = (i >> 6) & 255, h = i >> 14;
    wB[h * 16384 + o * FIN + f] = f2bf(w[i]);
  }
}

// ---------------------------------------------------------------------------
// Stage A: h = recx @ w per head (MFMA), no LDS, no barriers.
//          writes hT[b,h,o,n] bf16, s/d fp32.
// grid (8 h, 16 n-tiles(64), 8 b), block 256 (4 waves, wave = 16 rows)
// ---------------------------------------------------------------------------
__global__ __launch_bounds__(256, 4) void stageA(
    const unsigned short* __restrict__ recx,
    const unsigned short* __restrict__ wB,
    const float* __restrict__ a_src, const float* __restrict__ a_dst,
    unsigned short* __restrict__ hT,
    float* __restrict__ sbuf, float* __restrict__ dbuf)
{
  const int t = threadIdx.x;
  const int h = blockIdx.x, n0 = blockIdx.y * 64, b = blockIdx.z;
  const int wave = t >> 6, lane = t & 63, quad = lane >> 4, l15 = lane & 15;
  const int nrow = n0 + 16 * wave + l15;

  const unsigned short* ap = recx + (b * NN + nrow) * FIN + quad * 8;
  const unsigned short* wp = wB + h * 16384 + l15 * FIN + quad * 8;

  U8 afr[8];
  #pragma unroll
  for (int kc = 0; kc < 8; kc++) afr[kc].u = *(const u16x8*)(ap + kc * 32);

  f32x4 acc[4] = {};
  #pragma unroll
  for (int kc = 0; kc < 8; kc++){
    U8 bf[4];
    #pragma unroll
    for (int ss = 0; ss < 4; ss++) bf[ss].u = *(const u16x8*)(wp + ss * 4096 + kc * 32);
    #pragma unroll
    for (int ss = 0; ss < 4; ss++)
      acc[ss] = __builtin_amdgcn_mfma_f32_16x16x32_bf16(afr[kc].b, bf[ss].b, acc[ss], 0, 0, 0);
  }

  // hT store: C/D layout col(o)=l15, row(n)=quad*4+i -> lane holds 4 consecutive n
  unsigned short* hp = hT + ((b * NH + h) * FO) * NN + n0 + 16 * wave + quad * 4;
  #pragma unroll
  for (int ss = 0; ss < 4; ss++){
    u16x4 v;
    #pragma unroll
    for (int i = 0; i < 4; i++) v[i] = f2bf(acc[ss][i]);
    *(u16x4*)(hp + (16 * ss + l15) * NN) = v;
  }

  // s = h.a_src, d = h.a_dst (reduce over o)
  float as4[4], ad4[4];
  #pragma unroll
  for (int ss = 0; ss < 4; ss++){
    as4[ss] = a_src[h * FO + 16 * ss + l15];
    ad4[ss] = a_dst[h * FO + 16 * ss + l15];
  }
  #pragma unroll
  for (int i = 0; i < 4; i++){
    float ps = 0.f, pd = 0.f;
    #pragma unroll
    for (int ss = 0; ss < 4; ss++){ ps += acc[ss][i] * as4[ss]; pd += acc[ss][i] * ad4[ss]; }
    #pragma unroll
    for (int off = 1; off < 16; off <<= 1){
      ps += __shfl_xor(ps, off);
      pd += __shfl_xor(pd, off);
    }
    if (l15 == 0){
      const int row = n0 + 16 * wave + quad * 4 + i;
      sbuf[(b * NH + h) * NN + row] = ps;
      dbuf[(b * NH + h) * NN + row] = pd;
    }
  }
}

// ---------------------------------------------------------------------------
// Stage B: fused masked-softmax aggregation, barrier-free main loop.
// grid (32 n-tiles(32), 8 b), block 512 (8 waves = 8 heads, 32 rows each).
// P computed directly in MFMA A-frag layout: lane -> P[rh*16+l15][mc+quad*8+j]
// ---------------------------------------------------------------------------
__global__ __launch_bounds__(512, 2) void stageB(
    const int* __restrict__ A,
    const unsigned short* __restrict__ hT,
    const float* __restrict__ sbuf,
    const float* __restrict__ dbuf,
    const float* __restrict__ bias,
    const float* __restrict__ mz,
    float* __restrict__ out)
{
  __shared__ float d_l[NH * NN];     // 32 KB, wave-private slices
  __shared__ float l_l[NH * 32];
  __shared__ float oacc[32 * FO];    // 8 KB
  const int t = threadIdx.x, b = blockIdx.y, n0 = blockIdx.x * 32;
  const int h = t >> 6, lane = t & 63, quad = lane >> 4, l15 = lane & 15;

  for (int i = t; i < 2048; i += 512) oacc[i] = 0.f;

  // preload this head's d into wave-private LDS
  const float* dsrc = dbuf + (b * NH + h) * NN;
  float* dl = d_l + h * NN;
  #pragma unroll
  for (int it = 0; it < 4; it++)
    *(f32x4*)(dl + it * 256 + lane * 4) = *(const f32x4*)(dsrc + it * 256 + lane * 4);

  const float sv0 = sbuf[(b * NH + h) * NN + n0 + l15];
  const float sv1 = sbuf[(b * NH + h) * NN + n0 + 16 + l15];
  __syncthreads();                   // oacc init visible to all waves

  const unsigned short* hTb = hT + (b * NH + h) * FO * NN;
  const int* A0 = A + (b * NN + n0 + l15) * NN + quad * 8;
  const int* A1 = A0 + 16 * NN;

  // prefetch chunk 0
  i32x4 a00 = *(const i32x4*)(A0),     a01 = *(const i32x4*)(A0 + 4);
  i32x4 a10 = *(const i32x4*)(A1),     a11 = *(const i32x4*)(A1 + 4);
  U8 bfr[4];
  #pragma unroll
  for (int ss = 0; ss < 4; ss++)
    bfr[ss].u = *(const u16x8*)(hTb + (16 * ss + l15) * NN + quad * 8);

  float lp0 = 0.f, lp1 = 0.f;
  f32x4 acc[2][4] = {};

  for (int mc = 0; mc < NN; mc += 32){
    const i32x4 ca00 = a00, ca01 = a01, ca10 = a10, ca11 = a11;
    U8 cb[4];
    #pragma unroll
    for (int ss = 0; ss < 4; ss++) cb[ss] = bfr[ss];
    if (mc + 32 < NN){               // prefetch next chunk
      a00 = *(const i32x4*)(A0 + mc + 32); a01 = *(const i32x4*)(A0 + mc + 36);
      a10 = *(const i32x4*)(A1 + mc + 32); a11 = *(const i32x4*)(A1 + mc + 36);
      #pragma unroll
      for (int ss = 0; ss < 4; ss++)
        bfr[ss].u = *(const u16x8*)(hTb + (16 * ss + l15) * NN + mc + 32 + quad * 8);
    }
    f32x4 d0 = *(const f32x4*)(dl + mc + quad * 8);
    f32x4 d1 = *(const f32x4*)(dl + mc + quad * 8 + 4);

    float p0f[8], p1f[8];
    #pragma unroll
    for (int j = 0; j < 8; j++){
      const float dj  = (j < 4) ? d0[j] : d1[j - 4];
      const int   aj0 = (j < 4) ? ca00[j] : ca01[j - 4];
      const int   aj1 = (j < 4) ? ca10[j] : ca11[j - 4];
      float z0 = sv0 + dj, z1 = sv1 + dj;
      z0 = fmaxf(z0, 0.2f * z0);     // leaky_relu
      z1 = fmaxf(z1, 0.2f * z1);
      const float e0 = __expf(z0), e1 = __expf(z1);
      const float q0 = (aj0 > 0) ? e0 : 0.f;
      const float q1 = (aj1 > 0) ? e1 : 0.f;
      lp0 += q0; lp1 += q1;
      p0f[j] = q0; p1f[j] = q1;
    }
    U8 p0, p1;
    #pragma unroll
    for (int r = 0; r < 4; r++){
      p0.w[r] = pack_bf16(p0f[2 * r], p0f[2 * r + 1]);
      p1.w[r] = pack_bf16(p1f[2 * r], p1f[2 * r + 1]);
    }
    #pragma unroll
    for (int ss = 0; ss < 4; ss++)
      acc[0][ss] = __builtin_amdgcn_mfma_f32_16x16x32_bf16(p0.b, cb[ss].b, acc[0][ss], 0, 0, 0);
    #pragma unroll
    for (int ss = 0; ss < 4; ss++)
      acc[1][ss] = __builtin_amdgcn_mfma_f32_16x16x32_bf16(p1.b, cb[ss].b, acc[1][ss], 0, 0, 0);
  }

  // row denominators: reduce over quads (each quad held a 8-col slice per chunk)
  lp0 += __shfl_xor(lp0, 16); lp0 += __shfl_xor(lp0, 32);
  lp1 += __shfl_xor(lp1, 16); lp1 += __shfl_xor(lp1, 32);
  if (lane < 16){                    // wave-private l_l slice; DS ops in-order
    l_l[h * 32 + lane]      = lp0;
    l_l[h * 32 + 16 + lane] = lp1;
  }

  // normalize (1/8 head avg folded in) and head-sum into oacc
  #pragma unroll
  for (int rh = 0; rh < 2; rh++){
    float inv[4];
    #pragma unroll
    for (int i = 0; i < 4; i++)
      inv[i] = 0.125f / l_l[h * 32 + rh * 16 + quad * 4 + i];
    #pragma unroll
    for (int ss = 0; ss < 4; ss++)
      #pragma unroll
      for (int i = 0; i < 4; i++){
        const int row = rh * 16 + quad * 4 + i;
        atomicAdd(&oacc[row * FO + ss * 16 + l15], acc[rh][ss][i] * inv[i]);
      }
  }
  __syncthreads();

  for (int i = t; i < 2048; i += 512){
    const int row = i >> 6, o = i & 63;
    out[(b * NN + n0 + row) * FO + o] = (oacc[i] + bias[o]) * mz[b * NN + n0 + row];
  }
}

extern "C" void kernel_launch(void* const* d_in, const int* in_sizes, int n_in,
                              void* d_out, int out_size, void* d_ws, size_t ws_size,
                              hipStream_t stream)
{
  (void)in_sizes; (void)n_in; (void)out_size; (void)ws_size;
  const float* x    = (const float*)d_in[0];
  const int*   A    = (const int*)d_in[1];
  const float* mz   = (const float*)d_in[2];
  const float* e_at = (const float*)d_in[4];
  const float* Np   = (const float*)d_in[5];
  const float* w    = (const float*)d_in[6];
  const float* asrc = (const float*)d_in[7];
  const float* adst = (const float*)d_in[8];
  const float* bias = (const float*)d_in[9];
  float* out = (float*)d_out;

  char* ws = (char*)d_ws;
  unsigned short* recx = (unsigned short*)ws;                    // 4 MB
  unsigned short* wBuf = (unsigned short*)(ws + 4194304);        // 256 KB
  unsigned short* hT   = (unsigned short*)(ws + 4194304 + 262144);          // 8 MB
  float* sbuf = (float*)(ws + 4194304 + 262144 + 8388608);                  // 256 KB
  float* dbuf = (float*)(ws + 4194304 + 262144 + 8388608 + 262144);         // 256 KB

  stage0<<<dim3(256), dim3(256), 0, stream>>>(x, e_at, Np, w, recx, wBuf);
  stageA<<<dim3(8, 16, 8), dim3(256), 0, stream>>>(recx, wBuf, asrc, adst, hT, sbuf, dbuf);
  stageB<<<dim3(32, 8), dim3(512), 0, stream>>>(A, hT, sbuf, dbuf, bias, mz, out);
}